// Round 1
// baseline (162.984 us; speedup 1.0000x reference)
//
#include <hip/hip_runtime.h>

// RoPE sin/cos table gather:
//   out[pos_idx, 2k]   = cache[p, k, 1]  (cos)
//   out[pos_idx, 2k+1] = cache[p, k, 0]  (sin)
// cache row is contiguous 512 floats: [sin0, cos0, sin1, cos1, ...]
// -> per-float4 pairwise swap, fully coalesced 16B/lane loads and stores.
//
// V2: ILP-batched. Each 32-thread group handles FOUR consecutive positions:
//  - one int4 load fetches all 4 position indices (1 serialized lookup, not 4)
//  - 16 independent gather loads + 16 NT stores in flight per thread
//    (512B read + 512B written per thread vs 64B+64B before)
// This attacks the latency chain (pos load -> addr -> gather -> store), which
// kept the V1 kernel at ~3.3 TB/s effective vs the ~6.5 TB/s fill ceiling.
//
// NOTE: __builtin_nontemporal_store requires a NATIVE vector type, not
// HIP_vector_type<float,4> — use ext_vector_type(4).

#define EMBED_DIM 512
#define POS_PER_GROUP 4              // positions handled per 32-thread group

typedef float v4f __attribute__((ext_vector_type(4)));
typedef int   v4i __attribute__((ext_vector_type(4)));

__device__ __forceinline__ v4f swap_pairs(v4f v) {
    // (sin0, cos0, sin1, cos1) -> (cos0, sin0, cos1, sin1)
    return (v4f){v.y, v.x, v.w, v.z};
}

__device__ __forceinline__ void do_one_pos(int sub, int p,
                                           const float* __restrict__ cache,
                                           float* __restrict__ dst_row) {
    const v4f* __restrict__ src = (const v4f*)(cache + (size_t)p * EMBED_DIM);
    v4f* __restrict__ dst       = (v4f*)dst_row;
    v4f v0 = src[sub];
    v4f v1 = src[sub + 32];
    v4f v2 = src[sub + 64];
    v4f v3 = src[sub + 96];
    __builtin_nontemporal_store(swap_pairs(v0), &dst[sub]);
    __builtin_nontemporal_store(swap_pairs(v1), &dst[sub + 32]);
    __builtin_nontemporal_store(swap_pairs(v2), &dst[sub + 64]);
    __builtin_nontemporal_store(swap_pairs(v3), &dst[sub + 96]);
}

__global__ __launch_bounds__(256) void ScalarRoPEEmbedding_83769042141635_kernel(
    const int* __restrict__ positions,
    const float* __restrict__ cache,
    float* __restrict__ out,
    int n_pos)
{
    int tid   = blockIdx.x * blockDim.x + threadIdx.x;
    int group = tid >> 5;            // which group of POS_PER_GROUP positions
    int sub   = tid & 31;            // lane-within-group: owns 4 float4 per row
    int base  = group * POS_PER_GROUP;
    if (base >= n_pos) return;

    if (base + POS_PER_GROUP <= n_pos) {
        // Fast path: one 16B load for all 4 indices (base % 4 == 0 -> aligned).
        v4i p4 = *(const v4i*)(positions + base);

        const v4f* __restrict__ s0 = (const v4f*)(cache + (size_t)p4.x * EMBED_DIM);
        const v4f* __restrict__ s1 = (const v4f*)(cache + (size_t)p4.y * EMBED_DIM);
        const v4f* __restrict__ s2 = (const v4f*)(cache + (size_t)p4.z * EMBED_DIM);
        const v4f* __restrict__ s3 = (const v4f*)(cache + (size_t)p4.w * EMBED_DIM);

        // 16 independent loads in flight.
        v4f a00 = s0[sub], a01 = s0[sub + 32], a02 = s0[sub + 64], a03 = s0[sub + 96];
        v4f a10 = s1[sub], a11 = s1[sub + 32], a12 = s1[sub + 64], a13 = s1[sub + 96];
        v4f a20 = s2[sub], a21 = s2[sub + 32], a22 = s2[sub + 64], a23 = s2[sub + 96];
        v4f a30 = s3[sub], a31 = s3[sub + 32], a32 = s3[sub + 64], a33 = s3[sub + 96];

        v4f* __restrict__ d0 = (v4f*)(out + (size_t)(base + 0) * EMBED_DIM);
        v4f* __restrict__ d1 = (v4f*)(out + (size_t)(base + 1) * EMBED_DIM);
        v4f* __restrict__ d2 = (v4f*)(out + (size_t)(base + 2) * EMBED_DIM);
        v4f* __restrict__ d3 = (v4f*)(out + (size_t)(base + 3) * EMBED_DIM);

        __builtin_nontemporal_store(swap_pairs(a00), &d0[sub]);
        __builtin_nontemporal_store(swap_pairs(a01), &d0[sub + 32]);
        __builtin_nontemporal_store(swap_pairs(a02), &d0[sub + 64]);
        __builtin_nontemporal_store(swap_pairs(a03), &d0[sub + 96]);
        __builtin_nontemporal_store(swap_pairs(a10), &d1[sub]);
        __builtin_nontemporal_store(swap_pairs(a11), &d1[sub + 32]);
        __builtin_nontemporal_store(swap_pairs(a12), &d1[sub + 64]);
        __builtin_nontemporal_store(swap_pairs(a13), &d1[sub + 96]);
        __builtin_nontemporal_store(swap_pairs(a20), &d2[sub]);
        __builtin_nontemporal_store(swap_pairs(a21), &d2[sub + 32]);
        __builtin_nontemporal_store(swap_pairs(a22), &d2[sub + 64]);
        __builtin_nontemporal_store(swap_pairs(a23), &d2[sub + 96]);
        __builtin_nontemporal_store(swap_pairs(a30), &d3[sub]);
        __builtin_nontemporal_store(swap_pairs(a31), &d3[sub + 32]);
        __builtin_nontemporal_store(swap_pairs(a32), &d3[sub + 64]);
        __builtin_nontemporal_store(swap_pairs(a33), &d3[sub + 96]);
    } else {
        // Tail: fewer than POS_PER_GROUP positions left.
        for (int i = base; i < n_pos; ++i) {
            int p = positions[i];
            do_one_pos(sub, p, cache, out + (size_t)i * EMBED_DIM);
        }
    }
}

extern "C" void kernel_launch(void* const* d_in, const int* in_sizes, int n_in,
                              void* d_out, int out_size, void* d_ws, size_t ws_size,
                              hipStream_t stream) {
    const int*   positions = (const int*)d_in[0];
    const float* cache     = (const float*)d_in[1];
    float*       out       = (float*)d_out;

    int n_pos    = in_sizes[0];                              // 8 * 8192 = 65536
    int n_groups = (n_pos + POS_PER_GROUP - 1) / POS_PER_GROUP;
    int total_threads = n_groups * 32;                       // 524288 threads
    int block = 256;
    int grid  = (total_threads + block - 1) / block;         // 2048 blocks = 8/CU

    ScalarRoPEEmbedding_83769042141635_kernel<<<grid, block, 0, stream>>>(
        positions, cache, out, n_pos);
}